// Round 1
// baseline (1514.743 us; speedup 1.0000x reference)
//
#include <hip/hip_runtime.h>
#include <math.h>

#define NN 50000
#define PP 5000
#define GG 10
#define EE 800000
#define FF 92
#define LL 64
#define SLOPE 0.2f

static __device__ __forceinline__ float lrelu(float x){ return x > 0.f ? x : SLOPE*x; }

// ---------------- CSR build ----------------
__global__ void count_edges(const int* __restrict__ dst, int* __restrict__ cnt, int E){
  int e = blockIdx.x*blockDim.x + threadIdx.x;
  if (e < E) atomicAdd(&cnt[dst[e]], 1);
}

// cnt in: per-node counts; out: cursor (= row start). row_ptr gets exclusive prefix + total.
__global__ void prefix_kernel(int* __restrict__ cnt, int* __restrict__ row_ptr, int n){
  __shared__ int sh[1024];
  int t = threadIdx.x;
  int chunk = (n + 1023) >> 10;
  int start = t*chunk;
  int end = start + chunk; if (end > n) end = n;
  int s = 0;
  for (int i=start;i<end;++i) s += cnt[i];
  sh[t] = s; __syncthreads();
  for (int off=1; off<1024; off<<=1){
    int v = (t>=off) ? sh[t-off] : 0;
    __syncthreads();
    sh[t] += v;
    __syncthreads();
  }
  int run = (t==0) ? 0 : sh[t-1];
  for (int i=start;i<end;++i){ int c = cnt[i]; row_ptr[i]=run; cnt[i]=run; run += c; }
  if (t==1023) row_ptr[n] = run;
}

__global__ void scatter_edges(const int* __restrict__ dst, const int* __restrict__ eoff,
                              int* __restrict__ cursor, int* __restrict__ srcs, int E){
  int e = blockIdx.x*blockDim.x + threadIdx.x;
  if (e >= E) return;
  int d = dst[e];
  int pos = atomicAdd(&cursor[d], 1);
  srcs[pos] = (d/PP)*PP + eoff[e];
}

// ---------------- fp32 tiled GEMM: C[N,M] = X[N,K] @ W[K,M] ----------------
template<int BM,int BN,int BK,int TM,int TN>
__global__ void gemm_kernel(const float* __restrict__ X, const float* __restrict__ W,
                            float* __restrict__ C, int N, int K, int M){
  __shared__ float Xs[BM][BK];
  __shared__ float Ws[BK][BN];
  const int tid = threadIdx.x;
  const int tx = tid % (BN/TN);
  const int ty = tid / (BN/TN);
  const int brow = blockIdx.x * BM;
  const int bcol = blockIdx.y * BN;
  float acc[TM][TN];
  #pragma unroll
  for (int i=0;i<TM;++i)
    #pragma unroll
    for (int j=0;j<TN;++j) acc[i][j]=0.f;
  for (int k0=0;k0<K;k0+=BK){
    for (int i=tid;i<BM*BK;i+=256){
      int r = i / BK, c = i % BK;
      int gr = brow + r, gc = k0 + c;
      Xs[r][c] = (gr < N && gc < K) ? X[(size_t)gr*K + gc] : 0.f;
    }
    for (int i=tid;i<BK*BN;i+=256){
      int r = i / BN, c = i % BN;
      int gk = k0 + r;
      Ws[r][c] = (gk < K) ? W[(size_t)gk*M + bcol + c] : 0.f;
    }
    __syncthreads();
    #pragma unroll
    for (int kk=0;kk<BK;++kk){
      float xv[TM], wv[TN];
      #pragma unroll
      for (int i=0;i<TM;++i) xv[i] = Xs[ty*TM+i][kk];
      #pragma unroll
      for (int j=0;j<TN;++j) wv[j] = Ws[kk][tx*TN+j];
      #pragma unroll
      for (int i=0;i<TM;++i)
        #pragma unroll
        for (int j=0;j<TN;++j) acc[i][j] += xv[i]*wv[j];
    }
    __syncthreads();
  }
  #pragma unroll
  for (int i=0;i<TM;++i){
    int gr = brow + ty*TM + i;
    if (gr >= N) continue;
    float* cp = C + (size_t)gr*M + bcol + tx*TN;
    #pragma unroll
    for (int j=0;j<TN;++j) cp[j] = acc[i][j];
  }
}

// ---------------- el/er: el[n,h] = sum_d h[n,h,d]*al[h,d] ----------------
template<int D>
__global__ void eler_kernel(const float* __restrict__ h, const float* __restrict__ al,
                            const float* __restrict__ ar, float* __restrict__ el,
                            float* __restrict__ er, int N){
  constexpr int M = 4*D;
  int w = (blockIdx.x*blockDim.x + threadIdx.x) >> 6;
  int lane = threadIdx.x & 63;
  if (w >= N) return;
  const float* hp = h + (size_t)w*M;
  float pl0=0,pl1=0,pl2=0,pl3=0, pr0=0,pr1=0,pr2=0,pr3=0;
  #pragma unroll
  for (int k=0;k<M/64;++k){
    int m = lane + 64*k;
    float v = hp[m];
    float va = v*al[m], vb = v*ar[m];
    int hd = m / D;
    if (hd==0){ pl0+=va; pr0+=vb; }
    else if (hd==1){ pl1+=va; pr1+=vb; }
    else if (hd==2){ pl2+=va; pr2+=vb; }
    else { pl3+=va; pr3+=vb; }
  }
  #pragma unroll
  for (int off=32;off>=1;off>>=1){
    pl0 += __shfl_xor(pl0,off,64); pr0 += __shfl_xor(pr0,off,64);
    pl1 += __shfl_xor(pl1,off,64); pr1 += __shfl_xor(pr1,off,64);
    pl2 += __shfl_xor(pl2,off,64); pr2 += __shfl_xor(pr2,off,64);
    pl3 += __shfl_xor(pl3,off,64); pr3 += __shfl_xor(pr3,off,64);
  }
  if (lane==0){
    el[w*4+0]=pl0; el[w*4+1]=pl1; el[w*4+2]=pl2; el[w*4+3]=pl3;
    er[w*4+0]=pr0; er[w*4+1]=pr1; er[w*4+2]=pr2; er[w*4+3]=pr3;
  }
}

// ---------------- per-node edge softmax + aggregate ----------------
template<int D>
__global__ void gat_aggr(const float* __restrict__ hbuf, const float4* __restrict__ el4,
                         const float4* __restrict__ er4, const int* __restrict__ row_ptr,
                         const int* __restrict__ srcs, const float* __restrict__ bias,
                         float* __restrict__ out, int N){
  constexpr int M = 4*D;
  constexpr int R = M/64;
  int n = (blockIdx.x*blockDim.x + threadIdx.x) >> 6;
  int lane = threadIdx.x & 63;
  if (n >= N) return;
  int rs = row_ptr[n], re = row_ptr[n+1];
  float4 erv = er4[n];
  // pass 1: per-head max
  float mx0=-1e30f,mx1=-1e30f,mx2=-1e30f,mx3=-1e30f;
  for (int j=rs+lane; j<re; j+=64){
    int s = srcs[j];
    float4 ev = el4[s];
    mx0 = fmaxf(mx0, lrelu(ev.x+erv.x));
    mx1 = fmaxf(mx1, lrelu(ev.y+erv.y));
    mx2 = fmaxf(mx2, lrelu(ev.z+erv.z));
    mx3 = fmaxf(mx3, lrelu(ev.w+erv.w));
  }
  #pragma unroll
  for (int off=32;off>=1;off>>=1){
    mx0 = fmaxf(mx0, __shfl_xor(mx0,off,64));
    mx1 = fmaxf(mx1, __shfl_xor(mx1,off,64));
    mx2 = fmaxf(mx2, __shfl_xor(mx2,off,64));
    mx3 = fmaxf(mx3, __shfl_xor(mx3,off,64));
  }
  // pass 2: sum of exp
  float sm0=0,sm1=0,sm2=0,sm3=0;
  for (int j=rs+lane; j<re; j+=64){
    int s = srcs[j];
    float4 ev = el4[s];
    sm0 += __expf(lrelu(ev.x+erv.x)-mx0);
    sm1 += __expf(lrelu(ev.y+erv.y)-mx1);
    sm2 += __expf(lrelu(ev.z+erv.z)-mx2);
    sm3 += __expf(lrelu(ev.w+erv.w)-mx3);
  }
  #pragma unroll
  for (int off=32;off>=1;off>>=1){
    sm0 += __shfl_xor(sm0,off,64);
    sm1 += __shfl_xor(sm1,off,64);
    sm2 += __shfl_xor(sm2,off,64);
    sm3 += __shfl_xor(sm3,off,64);
  }
  float iv0 = sm0>0.f ? 1.f/sm0 : 0.f;
  float iv1 = sm1>0.f ? 1.f/sm1 : 0.f;
  float iv2 = sm2>0.f ? 1.f/sm2 : 0.f;
  float iv3 = sm3>0.f ? 1.f/sm3 : 0.f;
  // pass 3: weighted aggregate, lanes cover M dims
  float acc[R];
  #pragma unroll
  for (int k=0;k<R;++k) acc[k]=0.f;
  for (int j=rs; j<re; ++j){
    int s = srcs[j];
    float4 ev = el4[s];
    float a0 = __expf(lrelu(ev.x+erv.x)-mx0)*iv0;
    float a1 = __expf(lrelu(ev.y+erv.y)-mx1)*iv1;
    float a2 = __expf(lrelu(ev.z+erv.z)-mx2)*iv2;
    float a3 = __expf(lrelu(ev.w+erv.w)-mx3)*iv3;
    const float* hp = hbuf + (size_t)s*M;
    #pragma unroll
    for (int k=0;k<R;++k){
      int m = lane + 64*k;
      int hd = m / D;
      float ah = (hd==0)?a0:(hd==1)?a1:(hd==2)?a2:a3;
      acc[k] += ah * hp[m];
    }
  }
  #pragma unroll
  for (int k=0;k<R;++k){
    int m = lane + 64*k;
    float v = acc[k] + bias[m];
    out[(size_t)n*M + m] = v>0.f ? v : (__expf(v)-1.f);  // ELU
  }
}

// ---------------- gate = relu(h@gW1+gb1)@gW2+gb2 ----------------
__global__ void gate_kernel(const float* __restrict__ h, const float* __restrict__ gW1,
                            const float* __restrict__ gb1, const float* __restrict__ gW2,
                            const float* __restrict__ gb2, float* __restrict__ gate, int N){
  int n = (blockIdx.x*blockDim.x + threadIdx.x) >> 6;
  int lane = threadIdx.x & 63;
  if (n >= N) return;
  const float* hp = h + (size_t)n*512;
  float acc = gb1[lane];
  #pragma unroll 8
  for (int k=0;k<512;++k) acc += hp[k]*gW1[k*64+lane];
  acc = fmaxf(acc, 0.f);
  float g = acc * gW2[lane];
  #pragma unroll
  for (int off=32;off>=1;off>>=1) g += __shfl_xor(g,off,64);
  if (lane==0) gate[n] = g + gb2[0];
}

// ---------------- pooling stats: per-graph max & 1/sum ----------------
__global__ void pool_stats(const float* __restrict__ gate, float* __restrict__ stats){
  int g = blockIdx.x; int t = threadIdx.x; // 256
  __shared__ float red[256];
  float lm = -1e30f;
  for (int i=t;i<PP;i+=256) lm = fmaxf(lm, gate[g*PP+i]);
  red[t]=lm; __syncthreads();
  for (int o=128;o>0;o>>=1){ if(t<o) red[t]=fmaxf(red[t],red[t+o]); __syncthreads(); }
  float m = red[0]; __syncthreads();
  float ls = 0.f;
  for (int i=t;i<PP;i+=256) ls += __expf(gate[g*PP+i]-m);
  red[t]=ls; __syncthreads();
  for (int o=128;o>0;o>>=1){ if(t<o) red[t]+=red[t+o]; __syncthreads(); }
  if (t==0){ stats[g*2]=m; stats[g*2+1]=1.f/red[0]; }
}

// ---------------- pooling accumulate: emb[g,d] += sum_n a_n*h[n,d] ----------------
#define SL 40
__global__ void pool_accum(const float* __restrict__ h, const float* __restrict__ gate,
                           const float* __restrict__ stats, float* __restrict__ emb){
  int g = blockIdx.x / SL;
  int slice = blockIdx.x % SL;
  int d = threadIdx.x; // 512
  float m = stats[g*2], inv = stats[g*2+1];
  float acc = 0.f;
  for (int i=slice;i<PP;i+=SL){
    int nidx = g*PP + i;
    float w = __expf(gate[nidx]-m)*inv;
    acc += w * h[(size_t)nidx*512 + d];
  }
  atomicAdd(&emb[g*512+d], acc);
}

// ---------------- per-graph VAE heads + decoder rows ----------------
__global__ void decoder_kernel(const float* __restrict__ emb, const float* __restrict__ eps,
                               const float* __restrict__ Wmu, const float* __restrict__ bmu,
                               const float* __restrict__ Wlv, const float* __restrict__ blv,
                               const float* __restrict__ Wp, const float* __restrict__ bp,
                               const float* __restrict__ Wd1, const float* __restrict__ bd1,
                               const float* __restrict__ Wd2, const float* __restrict__ bd2,
                               float* __restrict__ out_mu, float* __restrict__ out_lv,
                               float* __restrict__ rowbuf){
  int g = blockIdx.x; int t = threadIdx.x; // 128
  __shared__ float z[64];
  __shared__ float hz[128];
  __shared__ float h2[64];
  const float* e = emb + g*512;
  if (t < 64){
    float mu = bmu[t], lv = blv[t];
    for (int k=0;k<512;++k){ float ev=e[k]; mu += ev*Wmu[k*64+t]; lv += ev*Wlv[k*64+t]; }
    out_mu[g*64+t]=mu; out_lv[g*64+t]=lv;
    z[t] = mu + __expf(0.5f*lv)*eps[g*64+t];
  }
  __syncthreads();
  {
    float a = bp[t];
    for (int k=0;k<64;++k) a += z[k]*Wp[k*128+t];
    hz[t] = fmaxf(a, 0.f);
  }
  __syncthreads();
  if (t < 64){
    float a = bd1[t];
    for (int k=0;k<128;++k) a += hz[k]*Wd1[k*64+t];
    h2[t] = fmaxf(a, 0.f);
  }
  __syncthreads();
  if (t < 92){
    float a = bd2[t];
    for (int k=0;k<64;++k) a += h2[k]*Wd2[k*92+t];
    rowbuf[g*92+t] = a;
  }
}

__global__ void broadcast_recon(const float* __restrict__ rowbuf, float* __restrict__ recon, int total){
  int idx = blockIdx.x*blockDim.x + threadIdx.x;
  if (idx >= total) return;
  int n = idx / 92;
  int f = idx - n*92;
  int g = n / PP;
  recon[idx] = rowbuf[g*92+f];
}

extern "C" void kernel_launch(void* const* d_in, const int* in_sizes, int n_in,
                              void* d_out, int out_size, void* d_ws, size_t ws_size,
                              hipStream_t stream){
  const float* node_feat = (const float*)d_in[0];
  const float* eps  = (const float*)d_in[1];
  const int* edge_dst = (const int*)d_in[2];
  const int* edge_off = (const int*)d_in[3];
  const float* W1=(const float*)d_in[4];  const float* al1=(const float*)d_in[5];
  const float* ar1=(const float*)d_in[6]; const float* b1=(const float*)d_in[7];
  const float* W2=(const float*)d_in[8];  const float* al2=(const float*)d_in[9];
  const float* ar2=(const float*)d_in[10];const float* b2=(const float*)d_in[11];
  const float* W3=(const float*)d_in[12]; const float* al3=(const float*)d_in[13];
  const float* ar3=(const float*)d_in[14];const float* b3=(const float*)d_in[15];
  const float* gW1=(const float*)d_in[16];const float* gb1=(const float*)d_in[17];
  const float* gW2=(const float*)d_in[18];const float* gb2=(const float*)d_in[19];
  const float* Wmu=(const float*)d_in[20];const float* bmu=(const float*)d_in[21];
  const float* Wlv=(const float*)d_in[22];const float* blv=(const float*)d_in[23];
  const float* Wp=(const float*)d_in[24]; const float* bp=(const float*)d_in[25];
  const float* Wd1=(const float*)d_in[26];const float* bd1=(const float*)d_in[27];
  const float* Wd2=(const float*)d_in[28];const float* bd2=(const float*)d_in[29];
  float* out = (float*)d_out;

  char* ws = (char*)d_ws;
  size_t off = 0;
  auto take = [&](size_t bytes)->char*{
    char* p = ws + off; off += (bytes + 255) & ~(size_t)255; return p;
  };
  int* row_ptr  = (int*)take((NN+1)*4);
  int* cursor   = (int*)take((size_t)NN*4);
  int* srcs     = (int*)take((size_t)EE*4);
  float* el     = (float*)take((size_t)NN*4*4);
  float* er     = (float*)take((size_t)NN*4*4);
  float* gate   = (float*)take((size_t)NN*4);
  float* stats  = (float*)take(GG*2*4);
  float* emb    = (float*)take(GG*512*4);
  float* rowbuf = (float*)take(GG*FF*4);
  float* hbuf   = (float*)take((size_t)NN*512*4);           // GEMM out, reused per layer
  char*  Rreg   = take((size_t)NN*512*4);                   // o1/o2/o3 time-shared region
  float* o1 = (float*)Rreg;                                  // dead after L2 GEMM
  float* o2 = (float*)(Rreg + (size_t)NN*128*4);             // dead after L3 GEMM
  float* o3 = (float*)Rreg;                                  // written after o1/o2 dead

  // CSR build
  hipMemsetAsync(cursor, 0, (size_t)NN*4, stream);
  count_edges<<<(EE+255)/256,256,0,stream>>>(edge_dst, cursor, EE);
  prefix_kernel<<<1,1024,0,stream>>>(cursor, row_ptr, NN);
  scatter_edges<<<(EE+255)/256,256,0,stream>>>(edge_dst, edge_off, cursor, srcs, EE);

  const int WBLK = (NN*64+255)/256; // wave-per-node grids

  // layer 1: 92 -> 4x32
  gemm_kernel<128,64,16,8,4><<<dim3((NN+127)/128,2),256,0,stream>>>(node_feat, W1, hbuf, NN, FF, 128);
  eler_kernel<32><<<WBLK,256,0,stream>>>(hbuf, al1, ar1, el, er, NN);
  gat_aggr<32><<<WBLK,256,0,stream>>>(hbuf, (const float4*)el, (const float4*)er, row_ptr, srcs, b1, o1, NN);

  // layer 2: 128 -> 4x64
  gemm_kernel<128,64,16,8,4><<<dim3((NN+127)/128,4),256,0,stream>>>(o1, W2, hbuf, NN, 128, 256);
  eler_kernel<64><<<WBLK,256,0,stream>>>(hbuf, al2, ar2, el, er, NN);
  gat_aggr<64><<<WBLK,256,0,stream>>>(hbuf, (const float4*)el, (const float4*)er, row_ptr, srcs, b2, o2, NN);

  // layer 3: 256 -> 4x128
  gemm_kernel<128,64,16,8,4><<<dim3((NN+127)/128,8),256,0,stream>>>(o2, W3, hbuf, NN, 256, 512);
  eler_kernel<128><<<WBLK,256,0,stream>>>(hbuf, al3, ar3, el, er, NN);
  gat_aggr<128><<<WBLK,256,0,stream>>>(hbuf, (const float4*)el, (const float4*)er, row_ptr, srcs, b3, o3, NN);

  // gate + pooling
  gate_kernel<<<WBLK,256,0,stream>>>(o3, gW1, gb1, gW2, gb2, gate, NN);
  pool_stats<<<GG,256,0,stream>>>(gate, stats);
  hipMemsetAsync(emb, 0, GG*512*4, stream);
  pool_accum<<<GG*SL,512,0,stream>>>(o3, gate, stats, emb);

  // VAE heads + decoder (10 unique rows) + broadcast
  float* out_mu = out + (size_t)NN*FF;
  float* out_lv = out_mu + GG*LL;
  decoder_kernel<<<GG,128,0,stream>>>(emb, eps, Wmu,bmu,Wlv,blv,Wp,bp,Wd1,bd1,Wd2,bd2,
                                      out_mu, out_lv, rowbuf);
  broadcast_recon<<<((NN*FF)+255)/256,256,0,stream>>>(rowbuf, out, NN*FF);
}